// Round 4
// baseline (14741.873 us; speedup 1.0000x reference)
//
#include <hip/hip_runtime.h>
#include <hip/hip_cooperative_groups.h>
#include <math.h>

namespace cg = cooperative_groups;

typedef __attribute__((ext_vector_type(8))) short bf16x8;
typedef __attribute__((ext_vector_type(4))) float f32x4;
typedef unsigned short u16;

namespace {
constexpr int Bc = 64, Tc = 12, Nn = 1024, Hc = 64, Ec = 10;
constexpr int NB = Nn * Bc;  // 65536
constexpr int Cc = 66;       // unified channel count (enc uses 65, col 65 zeroed)
constexpr int SA = 208;      // XA row stride ([X(66)|Y1(66)|Y2(66)|pad10])
constexpr int KP = 224;      // padded K for gate/update GEMMs (7 x 32)
constexpr int TN = Tc * Nn;  // 12288
}

// bank-group swizzle: chunk (r,kc) at 16B-unit ci = r*4 + (kc ^ SWZ(r)) -> 2-way (free)
#define SWZ(r) (((r) >> 1) & 3)

__device__ __forceinline__ void gld16(const void* g, void* l) {
  __builtin_amdgcn_global_load_lds(
      (const __attribute__((address_space(1))) void*)g,
      (__attribute__((address_space(3))) void*)l, 16, 0, 0);
}

__device__ __forceinline__ void split_bf(float v, u16& h, u16& l) {
  unsigned u = __float_as_uint(v);
  unsigned hu = (u + 0x7FFFu + ((u >> 16) & 1u)) & 0xFFFF0000u;
  h = (u16)(hu >> 16);
  float r = v - __uint_as_float(hu);
  unsigned u2 = __float_as_uint(r);
  l = (u16)((u2 + 0x7FFFu + ((u2 >> 16) & 1u)) >> 16);
}

struct Args {
  const float *x, *ycov, *emb, *fce;
  const float *egw, *egb, *euw, *eub, *dgw, *dgb, *duw, *dub, *pw, *pb;
  float* out;
  float *S1f, *S2f, *Hst, *Rb, *DE, *GO;
  u16 *S1h, *S1l, *S2h, *S2l, *XAh, *XAl, *Xth, *Xtl;
  u16 *WgeH, *WgeL, *WueH, *WueL, *WgdH, *WgdL, *WudH, *WudL;
};

// ---------- zero helpers (grid-stride, 16B stores) ----------
__device__ void ph_zero16(u16* p, size_t n16) {  // n16 multiple of 8
  uint4 z = {0u, 0u, 0u, 0u};
  uint4* q = (uint4*)p;
  size_t n = n16 / 8;
  for (size_t i = (size_t)blockIdx.x * 256 + threadIdx.x; i < n; i += (size_t)gridDim.x * 256)
    q[i] = z;
}
__device__ void ph_zerof(float* p, size_t nf) {  // nf multiple of 4
  float4 z = {0.f, 0.f, 0.f, 0.f};
  float4* q = (float4*)p;
  size_t n = nf / 4;
  for (size_t i = (size_t)blockIdx.x * 256 + threadIdx.x; i < n; i += (size_t)gridDim.x * 256)
    q[i] = z;
}

// ---------- weight prep ----------
__device__ void prep_one(const float* __restrict__ W, int Csrc, int ncol,
                         u16* __restrict__ Wh, u16* __restrict__ Wl) {
  int total = ncol * KP;
  for (int idx = blockIdx.x * 256 + threadIdx.x; idx < total; idx += gridDim.x * 256) {
    int n = idx / KP, kp = idx % KP;
    int chunk = kp / Cc, c = kp % Cc;
    float v = 0.f;
    if (kp < 3 * Cc && c < Csrc) v = W[((size_t)chunk * Csrc + c) * ncol + n];
    u16 h, l;
    split_bf(v, h, l);
    Wh[idx] = h; Wl[idx] = l;
  }
}

// ---------- G = in @ in^T (fp32, tiled) ----------
__device__ void ph_gram(const float* __restrict__ in, int Kd, float* __restrict__ G,
                        void* sm) {
  float(*At)[64] = (float(*)[64])sm;
  float(*Bt)[64] = (float(*)[64])((char*)sm + 4096);
  int tx = threadIdx.x & 15, ty = threadIdx.x >> 4;
  for (int tile = blockIdx.x; tile < 256; tile += gridDim.x) {
    int i0 = (tile >> 4) * 64, j0 = (tile & 15) * 64;
    float acc[4][4] = {};
    for (int k0 = 0; k0 < Kd; k0 += 16) {
      for (int u = threadIdx.x; u < 1024; u += 256) {
        int i = u >> 4, k = u & 15;
        At[k][i] = (k0 + k < Kd) ? in[(size_t)(i0 + i) * Kd + k0 + k] : 0.f;
      }
      for (int u = threadIdx.x; u < 1024; u += 256) {
        int j = u >> 4, k = u & 15;
        Bt[k][j] = (k0 + k < Kd) ? in[(size_t)(j0 + j) * Kd + k0 + k] : 0.f;
      }
      __syncthreads();
#pragma unroll
      for (int kk = 0; kk < 16; kk++) {
        float a[4], b[4];
#pragma unroll
        for (int p = 0; p < 4; p++) a[p] = At[kk][ty * 4 + p];
#pragma unroll
        for (int q = 0; q < 4; q++) b[q] = Bt[kk][tx * 4 + q];
#pragma unroll
        for (int p = 0; p < 4; p++)
#pragma unroll
          for (int q = 0; q < 4; q++) acc[p][q] = fmaf(a[p], b[q], acc[p][q]);
      }
      __syncthreads();
    }
    for (int p = 0; p < 4; p++)
      for (int q = 0; q < 4; q++)
        G[(size_t)(i0 + ty * 4 + p) * Nn + j0 + tx * 4 + q] = acc[p][q];
  }
}

// ---------- S = row_softmax(relu(G)) ----------
__device__ void ph_softmax(const float* __restrict__ G, float* __restrict__ S, void* sm) {
  float* sred = (float*)sm;
  for (int n = blockIdx.x; n < Nn; n += gridDim.x) {
    float v[4];
#pragma unroll
    for (int i = 0; i < 4; i++)
      v[i] = fmaxf(G[(size_t)n * Nn + threadIdx.x + i * 256], 0.f);
    float mx = fmaxf(fmaxf(v[0], v[1]), fmaxf(v[2], v[3]));
    for (int off = 32; off > 0; off >>= 1) mx = fmaxf(mx, __shfl_down(mx, off));
    if ((threadIdx.x & 63) == 0) sred[threadIdx.x >> 6] = mx;
    __syncthreads();
    float rmax = fmaxf(fmaxf(sred[0], sred[1]), fmaxf(sred[2], sred[3]));
    float s = 0.f;
#pragma unroll
    for (int i = 0; i < 4; i++) { v[i] = expf(v[i] - rmax); s += v[i]; }
    for (int off = 32; off > 0; off >>= 1) s += __shfl_down(s, off);
    if ((threadIdx.x & 63) == 0) sred[4 + (threadIdx.x >> 6)] = s;
    __syncthreads();
    float inv = 1.f / (sred[4] + sred[5] + sred[6] + sred[7]);
#pragma unroll
    for (int i = 0; i < 4; i++) S[(size_t)n * Nn + threadIdx.x + i * 256] = v[i] * inv;
    __syncthreads();
  }
}

// ---------- S2 = 2*S@S - I ----------
__device__ void ph_s2(const float* __restrict__ S, float* __restrict__ S2, void* sm) {
  float(*At)[64] = (float(*)[64])sm;
  float(*Bt)[64] = (float(*)[64])((char*)sm + 4096);
  int tx = threadIdx.x & 15, ty = threadIdx.x >> 4;
  for (int tile = blockIdx.x; tile < 256; tile += gridDim.x) {
    int i0 = (tile >> 4) * 64, j0 = (tile & 15) * 64;
    float acc[4][4] = {};
    for (int k0 = 0; k0 < Nn; k0 += 16) {
      for (int u = threadIdx.x; u < 1024; u += 256) {
        int i = u >> 4, k = u & 15;
        At[k][i] = S[(size_t)(i0 + i) * Nn + k0 + k];
      }
      for (int u = threadIdx.x; u < 1024; u += 256) {
        int k = u >> 6, j = u & 63;
        Bt[k][j] = S[(size_t)(k0 + k) * Nn + j0 + j];
      }
      __syncthreads();
#pragma unroll
      for (int kk = 0; kk < 16; kk++) {
        float a[4], b[4];
#pragma unroll
        for (int p = 0; p < 4; p++) a[p] = At[kk][ty * 4 + p];
#pragma unroll
        for (int q = 0; q < 4; q++) b[q] = Bt[kk][tx * 4 + q];
#pragma unroll
        for (int p = 0; p < 4; p++)
#pragma unroll
          for (int q = 0; q < 4; q++) acc[p][q] = fmaf(a[p], b[q], acc[p][q]);
      }
      __syncthreads();
    }
    for (int p = 0; p < 4; p++)
      for (int q = 0; q < 4; q++) {
        int i = i0 + ty * 4 + p, j = j0 + tx * 4 + q;
        S2[(size_t)i * Nn + j] = 2.f * acc[p][q] - (i == j ? 1.f : 0.f);
      }
  }
}

// ---------- split S1,S2 -> bf16 hi/lo ----------
__device__ void ph_split2(const float* __restrict__ A, const float* __restrict__ B,
                          u16* __restrict__ Ah, u16* __restrict__ Al,
                          u16* __restrict__ Bh, u16* __restrict__ Bl) {
  for (int i = blockIdx.x * 256 + threadIdx.x; i < Nn * Nn; i += gridDim.x * 256) {
    u16 h, l;
    split_bf(A[i], h, l); Ah[i] = h; Al[i] = l;
    split_bf(B[i], h, l); Bh[i] = h; Bl[i] = l;
  }
}

// ---------- Xt build + XA col0/1 fill (mode 0 enc, 1 dec) ----------
__device__ void ph_bxt(const float* __restrict__ x, const float* __restrict__ ycov,
                       const float* __restrict__ go, const float* __restrict__ h,
                       u16* __restrict__ Xth, u16* __restrict__ Xtl,
                       u16* __restrict__ XAh, u16* __restrict__ XAl, int t, int mode,
                       void* sm) {
  float(*sx)[67] = (float(*)[67])sm;
  int tid = threadIdx.x;
  int off = (mode == 0) ? 1 : 2;
  for (int tile = blockIdx.x; tile < 1024; tile += gridDim.x) {
    int n0 = (tile & 15) * 64, b = tile >> 4;
    int hh = tid & 63, nq = tid >> 6;
#pragma unroll
    for (int i = 0; i < 16; i++) {
      int n = nq * 16 + i;
      sx[n][off + hh] = h[((size_t)(n0 + n) * 64 + b) * Hc + hh];
    }
    if (tid < 64) {
      int n = tid;
      if (mode == 0) {
        sx[n][0] = x[(size_t)b * TN + t * Nn + n0 + n];
        sx[n][65] = 0.f;
      } else {
        sx[n][0] = go[(size_t)(n0 + n) * 64 + b];
        sx[n][1] = ycov[(size_t)b * TN + t * Nn + n0 + n];
      }
    }
    __syncthreads();
    // fill XA col0 (and col1 for dec)
    if (tid < 64) {
      int n = tid;
      size_t row = (size_t)(n0 + n) * 64 + b;
      u16 vh, vl;
      split_bf(sx[n][0], vh, vl);
      XAh[row * SA] = vh; XAl[row * SA] = vl;
      if (mode == 1) {
        split_bf(sx[n][1], vh, vl);
        XAh[row * SA + 1] = vh; XAl[row * SA + 1] = vl;
      }
    }
    // transposed write
    int n = tid & 63, cq = tid >> 6;
    for (int c = cq; c < Cc; c += 4) {
      u16 vh, vl;
      split_bf(sx[n][c], vh, vl);
      size_t a = ((size_t)b * Cc + c) * Nn + n0 + n;
      Xth[a] = vh; Xtl[a] = vl;
    }
    __syncthreads();
  }
}

// ---------- state transpose XA -> Xt ----------
__device__ void ph_bxt_state(const u16* __restrict__ XAh, const u16* __restrict__ XAl,
                             u16* __restrict__ Xth, u16* __restrict__ Xtl, int off,
                             void* sm) {
  u16(*sh)[66] = (u16(*)[66])sm;
  u16(*sl)[66] = (u16(*)[66])((char*)sm + 8448);
  int tid = threadIdx.x;
  for (int tile = blockIdx.x; tile < 1024; tile += gridDim.x) {
    int n0 = (tile & 15) * 64, b = tile >> 4;
    for (int u = tid; u < 4096; u += 256) {
      int i = u >> 6, c = u & 63;
      size_t a = ((size_t)(n0 + i) * 64 + b) * SA + off + c;
      sh[i][c] = XAh[a];
      sl[i][c] = XAl[a];
    }
    __syncthreads();
    for (int u = tid; u < 4096; u += 256) {
      int c = u >> 6, i = u & 63;
      size_t a = ((size_t)b * Cc + off + c) * Nn + n0 + i;
      Xth[a] = sh[i][c];
      Xtl[a] = sl[i][c];
    }
    __syncthreads();
  }
}

// ---------- Y1 = S@X, Y2 = S2@X (split-bf16 MFMA) -> XA cols 66.. ----------
__device__ void ph_ygemm(const u16* __restrict__ S1h, const u16* __restrict__ S1l,
                         const u16* __restrict__ S2h, const u16* __restrict__ S2l,
                         const u16* __restrict__ Xth, const u16* __restrict__ Xtl,
                         u16* __restrict__ XAh, u16* __restrict__ XAl, void* sm) {
  u16* lds = (u16*)sm;
  const int tid = threadIdx.x;
  const int wave = tid >> 6, lane = tid & 63;
  const int wy = wave >> 1, wx = wave & 1;
  const int m = lane & 15, quad = lane >> 4;
  const int ar = tid >> 2;
  const int akc = (tid & 3) ^ SWZ(ar);
  const u16* amat[4] = {S1h, S1l, S2h, S2l};

  for (int tile = blockIdx.x; tile < 528; tile += gridDim.x) {
    int i0 = (tile / 33) * 64;
    int j0 = (tile % 33) * 128;
    f32x4 acc1[2][4], acc2[2][4];
    f32x4 z4 = {0.f, 0.f, 0.f, 0.f};
#pragma unroll
    for (int a = 0; a < 2; a++)
#pragma unroll
      for (int q = 0; q < 4; q++) { acc1[a][q] = z4; acc2[a][q] = z4; }

    for (int k0 = 0; k0 < Nn; k0 += 32) {
#pragma unroll
      for (int s = 0; s < 4; s++)
        gld16(amat[s] + (size_t)(i0 + ar) * Nn + k0 + akc * 8, &lds[s * 2048 + wave * 512]);
#pragma unroll
      for (int p = 0; p < 2; p++) {
        int r = p * 64 + (tid >> 2);
        int kc = (tid & 3) ^ SWZ(r);
        gld16(Xth + (size_t)(j0 + r) * Nn + k0 + kc * 8, &lds[8192 + p * 2048 + wave * 512]);
        gld16(Xtl + (size_t)(j0 + r) * Nn + k0 + kc * 8, &lds[12288 + p * 2048 + wave * 512]);
      }
      __syncthreads();

      bf16x8 a1h[2], a1l[2], a2h[2], a2l[2], bh[4], bl[4];
#pragma unroll
      for (int mb = 0; mb < 2; mb++) {
        int r = wy * 32 + mb * 16 + m;
        int ci = r * 4 + (quad ^ SWZ(r));
        a1h[mb] = *(const bf16x8*)&lds[0 * 2048 + ci * 8];
        a1l[mb] = *(const bf16x8*)&lds[1 * 2048 + ci * 8];
        a2h[mb] = *(const bf16x8*)&lds[2 * 2048 + ci * 8];
        a2l[mb] = *(const bf16x8*)&lds[3 * 2048 + ci * 8];
      }
#pragma unroll
      for (int nb = 0; nb < 4; nb++) {
        int rj = wx * 64 + nb * 16 + m;
        int cj = rj * 4 + (quad ^ SWZ(rj));
        bh[nb] = *(const bf16x8*)&lds[8192 + cj * 8];
        bl[nb] = *(const bf16x8*)&lds[12288 + cj * 8];
      }
#pragma unroll
      for (int mb = 0; mb < 2; mb++)
#pragma unroll
        for (int nb = 0; nb < 4; nb++) {
          acc1[mb][nb] = __builtin_amdgcn_mfma_f32_16x16x32_bf16(a1h[mb], bh[nb], acc1[mb][nb], 0, 0, 0);
          acc1[mb][nb] = __builtin_amdgcn_mfma_f32_16x16x32_bf16(a1h[mb], bl[nb], acc1[mb][nb], 0, 0, 0);
          acc1[mb][nb] = __builtin_amdgcn_mfma_f32_16x16x32_bf16(a1l[mb], bh[nb], acc1[mb][nb], 0, 0, 0);
          acc2[mb][nb] = __builtin_amdgcn_mfma_f32_16x16x32_bf16(a2h[mb], bh[nb], acc2[mb][nb], 0, 0, 0);
          acc2[mb][nb] = __builtin_amdgcn_mfma_f32_16x16x32_bf16(a2h[mb], bl[nb], acc2[mb][nb], 0, 0, 0);
          acc2[mb][nb] = __builtin_amdgcn_mfma_f32_16x16x32_bf16(a2l[mb], bh[nb], acc2[mb][nb], 0, 0, 0);
        }
      __syncthreads();
    }

#pragma unroll
    for (int mb = 0; mb < 2; mb++)
#pragma unroll
      for (int nb = 0; nb < 4; nb++) {
        int col = j0 + wx * 64 + nb * 16 + m;
        int bb = col / Cc, cc = col % Cc;
#pragma unroll
        for (int p = 0; p < 4; p++) {
          int row = i0 + wy * 32 + mb * 16 + quad * 4 + p;
          size_t base = ((size_t)row * 64 + bb) * SA;
          u16 vh, vl;
          split_bf(acc1[mb][nb][p], vh, vl);
          XAh[base + 66 + cc] = vh; XAl[base + 66 + cc] = vl;
          split_bf(acc2[mb][nb][p], vh, vl);
          XAh[base + 132 + cc] = vh; XAl[base + 132 + cc] = vl;
        }
      }
  }
}

// ---------- gate: sigmoid(XA@W^T+b) -> Rb; z*h into XA state cols ----------
__device__ void ph_gate(const u16* __restrict__ XAh, const u16* __restrict__ XAl,
                        const u16* __restrict__ Wh, const u16* __restrict__ Wl,
                        const float* __restrict__ bias, const float* __restrict__ hst,
                        float* __restrict__ Rb, u16* __restrict__ XAho,
                        u16* __restrict__ XAlo, int off, void* sm) {
  u16* lds = (u16*)sm;
  const int tid = threadIdx.x;
  const int wave = tid >> 6, lane = tid & 63;
  const int wy = wave >> 1, wx = wave & 1;
  const int m = lane & 15, quad = lane >> 4;

  for (int tile = blockIdx.x; tile < 512; tile += gridDim.x) {
    int r0 = tile * 128;
    f32x4 acc[4][4];
    f32x4 z4 = {0.f, 0.f, 0.f, 0.f};
#pragma unroll
    for (int a = 0; a < 4; a++)
#pragma unroll
      for (int q = 0; q < 4; q++) acc[a][q] = z4;

    for (int kt = 0; kt < 7; kt++) {
      int k0 = kt * 32;
#pragma unroll
      for (int p = 0; p < 2; p++) {
        int r = p * 64 + (tid >> 2);
        int kc = (tid & 3) ^ SWZ(r);
        gld16(XAh + (size_t)(r0 + r) * SA + k0 + kc * 8, &lds[p * 2048 + wave * 512]);
        gld16(XAl + (size_t)(r0 + r) * SA + k0 + kc * 8, &lds[4096 + p * 2048 + wave * 512]);
        gld16(Wh + (size_t)r * KP + k0 + kc * 8, &lds[8192 + p * 2048 + wave * 512]);
        gld16(Wl + (size_t)r * KP + k0 + kc * 8, &lds[12288 + p * 2048 + wave * 512]);
      }
      __syncthreads();

      bf16x8 ah[4], al[4], bh[4], bl[4];
#pragma unroll
      for (int mb = 0; mb < 4; mb++) {
        int r = wy * 64 + mb * 16 + m;
        int ci = r * 4 + (quad ^ SWZ(r));
        ah[mb] = *(const bf16x8*)&lds[ci * 8];
        al[mb] = *(const bf16x8*)&lds[4096 + ci * 8];
      }
#pragma unroll
      for (int nb = 0; nb < 4; nb++) {
        int rj = wx * 64 + nb * 16 + m;
        int cj = rj * 4 + (quad ^ SWZ(rj));
        bh[nb] = *(const bf16x8*)&lds[8192 + cj * 8];
        bl[nb] = *(const bf16x8*)&lds[12288 + cj * 8];
      }
#pragma unroll
      for (int mb = 0; mb < 4; mb++)
#pragma unroll
        for (int nb = 0; nb < 4; nb++) {
          acc[mb][nb] = __builtin_amdgcn_mfma_f32_16x16x32_bf16(ah[mb], bh[nb], acc[mb][nb], 0, 0, 0);
          acc[mb][nb] = __builtin_amdgcn_mfma_f32_16x16x32_bf16(ah[mb], bl[nb], acc[mb][nb], 0, 0, 0);
          acc[mb][nb] = __builtin_amdgcn_mfma_f32_16x16x32_bf16(al[mb], bh[nb], acc[mb][nb], 0, 0, 0);
        }
      __syncthreads();
    }

#pragma unroll
    for (int mb = 0; mb < 4; mb++)
#pragma unroll
      for (int nb = 0; nb < 4; nb++) {
        int col = wx * 64 + nb * 16 + m;
        float bv = bias[col];
#pragma unroll
        for (int p = 0; p < 4; p++) {
          int row = r0 + wy * 64 + mb * 16 + quad * 4 + p;
          float sg = 1.f / (1.f + expf(-(acc[mb][nb][p] + bv)));
          if (col < 64) {
            float v = sg * hst[(size_t)row * 64 + col];
            u16 vh, vl;
            split_bf(v, vh, vl);
            size_t a = (size_t)row * SA + off + col;
            XAho[a] = vh; XAlo[a] = vl;
          } else {
            Rb[(size_t)row * 64 + col - 64] = sg;
          }
        }
      }
  }
}

// ---------- update: hc = tanh(XA@Wu^T+b); h = r*h+(1-r)*hc; h -> XA state ----------
__device__ void ph_upd(const u16* __restrict__ XAh, const u16* __restrict__ XAl,
                       const u16* __restrict__ Wh, const u16* __restrict__ Wl,
                       const float* __restrict__ bias, const float* __restrict__ Rb,
                       float* __restrict__ h, u16* __restrict__ XAho,
                       u16* __restrict__ XAlo, int off_next, void* sm) {
  u16* lds = (u16*)sm;
  const int tid = threadIdx.x;
  const int wave = tid >> 6, lane = tid & 63;
  const int wy = wave >> 1, wx = wave & 1;
  const int m = lane & 15, quad = lane >> 4;

  for (int tile = blockIdx.x; tile < 512; tile += gridDim.x) {
    int r0 = tile * 128;
    f32x4 acc[4][2];
    f32x4 z4 = {0.f, 0.f, 0.f, 0.f};
#pragma unroll
    for (int a = 0; a < 4; a++) { acc[a][0] = z4; acc[a][1] = z4; }

    for (int kt = 0; kt < 7; kt++) {
      int k0 = kt * 32;
#pragma unroll
      for (int p = 0; p < 2; p++) {
        int r = p * 64 + (tid >> 2);
        int kc = (tid & 3) ^ SWZ(r);
        gld16(XAh + (size_t)(r0 + r) * SA + k0 + kc * 8, &lds[p * 2048 + wave * 512]);
        gld16(XAl + (size_t)(r0 + r) * SA + k0 + kc * 8, &lds[4096 + p * 2048 + wave * 512]);
      }
      {
        int r = tid >> 2;
        int kc = (tid & 3) ^ SWZ(r);
        gld16(Wh + (size_t)r * KP + k0 + kc * 8, &lds[8192 + wave * 512]);
        gld16(Wl + (size_t)r * KP + k0 + kc * 8, &lds[10240 + wave * 512]);
      }
      __syncthreads();

      bf16x8 ah[4], al[4], bh[2], bl[2];
#pragma unroll
      for (int mb = 0; mb < 4; mb++) {
        int r = wy * 64 + mb * 16 + m;
        int ci = r * 4 + (quad ^ SWZ(r));
        ah[mb] = *(const bf16x8*)&lds[ci * 8];
        al[mb] = *(const bf16x8*)&lds[4096 + ci * 8];
      }
#pragma unroll
      for (int nb = 0; nb < 2; nb++) {
        int rj = wx * 32 + nb * 16 + m;
        int cj = rj * 4 + (quad ^ SWZ(rj));
        bh[nb] = *(const bf16x8*)&lds[8192 + cj * 8];
        bl[nb] = *(const bf16x8*)&lds[10240 + cj * 8];
      }
#pragma unroll
      for (int mb = 0; mb < 4; mb++)
#pragma unroll
        for (int nb = 0; nb < 2; nb++) {
          acc[mb][nb] = __builtin_amdgcn_mfma_f32_16x16x32_bf16(ah[mb], bh[nb], acc[mb][nb], 0, 0, 0);
          acc[mb][nb] = __builtin_amdgcn_mfma_f32_16x16x32_bf16(ah[mb], bl[nb], acc[mb][nb], 0, 0, 0);
          acc[mb][nb] = __builtin_amdgcn_mfma_f32_16x16x32_bf16(al[mb], bh[nb], acc[mb][nb], 0, 0, 0);
        }
      __syncthreads();
    }

#pragma unroll
    for (int mb = 0; mb < 4; mb++)
#pragma unroll
      for (int nb = 0; nb < 2; nb++) {
        int col = wx * 32 + nb * 16 + m;
        float bv = bias[col];
#pragma unroll
        for (int p = 0; p < 4; p++) {
          int row = r0 + wy * 64 + mb * 16 + quad * 4 + p;
          float hc = tanhf(acc[mb][nb][p] + bv);
          size_t idx = (size_t)row * 64 + col;
          float rr = Rb[idx];
          float hn = rr * h[idx] + (1.f - rr) * hc;
          h[idx] = hn;
          u16 vh, vl;
          split_bf(hn, vh, vl);
          size_t a = (size_t)row * SA + off_next + col;
          XAho[a] = vh; XAlo[a] = vl;
        }
      }
  }
}

// ---------- de = h @ FC_E (per (n,b) row) ----------
__device__ void ph_de(const float* __restrict__ h, const float* __restrict__ fc,
                      float* __restrict__ de, void* sm) {
  float* fcs = (float*)sm;
  for (int j = threadIdx.x; j < Hc * Ec; j += 256) fcs[j] = fc[j];
  __syncthreads();
  for (int idx = blockIdx.x * 256 + threadIdx.x; idx < Nn * Bc * Ec;
       idx += gridDim.x * 256) {
    int n = idx / (Bc * Ec);
    int rem = idx % (Bc * Ec);
    int b = rem / Ec, e = rem % Ec;
    const float* hp = h + (size_t)n * (Bc * Hc) + (size_t)b * Hc;
    float acc = 0.f;
#pragma unroll 8
    for (int hh = 0; hh < Hc; hh++) acc = fmaf(hp[hh], fcs[hh * Ec + e], acc);
    de[idx] = acc;
  }
  __syncthreads();
}

__device__ void ph_go_init(const float* __restrict__ x, float* __restrict__ go) {
  for (int idx = blockIdx.x * 256 + threadIdx.x; idx < NB; idx += gridDim.x * 256) {
    int n = idx >> 6, b = idx & 63;
    go[idx] = x[(size_t)b * TN + (size_t)(Tc - 1) * Nn + n];
  }
}

__device__ void ph_proj(const float* __restrict__ h, const float* __restrict__ pw,
                        const float* __restrict__ pb, float* __restrict__ go,
                        float* __restrict__ out, int t) {
  for (int idx = blockIdx.x * 256 + threadIdx.x; idx < NB; idx += gridDim.x * 256) {
    int n = idx >> 6, b = idx & 63;
    const float* hp = h + (size_t)idx * Hc;
    float acc = pb[0];
#pragma unroll 8
    for (int i = 0; i < Hc; i++) acc = fmaf(hp[i], pw[i], acc);
    go[idx] = acc;
    out[(size_t)b * TN + (size_t)t * Nn + n] = acc;
  }
}

// ================= mega cooperative kernel =================
__global__ __launch_bounds__(256, 2) void mega(Args a) {
  cg::grid_group grid = cg::this_grid();
  __shared__ __align__(16) unsigned char SM[32768];

  // init: zero Hst + XA, prep weights
  ph_zerof(a.Hst, (size_t)NB * Hc);
  ph_zero16(a.XAh, (size_t)(NB + 4) * SA);
  ph_zero16(a.XAl, (size_t)(NB + 4) * SA);
  prep_one(a.egw, 65, 128, a.WgeH, a.WgeL);
  prep_one(a.euw, 65, 64, a.WueH, a.WueL);
  prep_one(a.dgw, 66, 128, a.WgdH, a.WgdL);
  prep_one(a.duw, 66, 64, a.WudH, a.WudL);
  grid.sync();

  // encoder supports
  ph_gram(a.emb, Ec, a.S2f, SM);
  grid.sync();
  ph_softmax(a.S2f, a.S1f, SM);
  grid.sync();
  ph_s2(a.S1f, a.S2f, SM);
  grid.sync();
  ph_split2(a.S1f, a.S2f, a.S1h, a.S1l, a.S2h, a.S2l);
  grid.sync();

  for (int t = 0; t < Tc; t++) {
    ph_bxt(a.x, nullptr, nullptr, a.Hst, a.Xth, a.Xtl, a.XAh, a.XAl, t, 0, SM);
    grid.sync();
    ph_ygemm(a.S1h, a.S1l, a.S2h, a.S2l, a.Xth, a.Xtl, a.XAh, a.XAl, SM);
    grid.sync();
    ph_gate(a.XAh, a.XAl, a.WgeH, a.WgeL, a.egb, a.Hst, a.Rb, a.XAh, a.XAl, 1, SM);
    grid.sync();
    ph_bxt_state(a.XAh, a.XAl, a.Xth, a.Xtl, 1, SM);
    grid.sync();
    ph_ygemm(a.S1h, a.S1l, a.S2h, a.S2l, a.Xth, a.Xtl, a.XAh, a.XAl, SM);
    grid.sync();
    ph_upd(a.XAh, a.XAl, a.WueH, a.WueL, a.eub, a.Rb, a.Hst, a.XAh, a.XAl,
           (t == Tc - 1) ? 2 : 1, SM);
    grid.sync();
  }

  // decoder supports
  ph_de(a.Hst, a.fce, a.DE, SM);
  ph_go_init(a.x, a.GO);
  grid.sync();
  ph_gram(a.DE, Bc * Ec, a.S2f, SM);
  grid.sync();
  ph_softmax(a.S2f, a.S1f, SM);
  grid.sync();
  ph_s2(a.S1f, a.S2f, SM);
  grid.sync();
  ph_split2(a.S1f, a.S2f, a.S1h, a.S1l, a.S2h, a.S2l);
  grid.sync();

  for (int t = 0; t < Tc; t++) {
    ph_bxt(nullptr, a.ycov, a.GO, a.Hst, a.Xth, a.Xtl, a.XAh, a.XAl, t, 1, SM);
    grid.sync();
    ph_ygemm(a.S1h, a.S1l, a.S2h, a.S2l, a.Xth, a.Xtl, a.XAh, a.XAl, SM);
    grid.sync();
    ph_gate(a.XAh, a.XAl, a.WgdH, a.WgdL, a.dgb, a.Hst, a.Rb, a.XAh, a.XAl, 2, SM);
    grid.sync();
    ph_bxt_state(a.XAh, a.XAl, a.Xth, a.Xtl, 2, SM);
    grid.sync();
    ph_ygemm(a.S1h, a.S1l, a.S2h, a.S2l, a.Xth, a.Xtl, a.XAh, a.XAl, SM);
    grid.sync();
    ph_upd(a.XAh, a.XAl, a.WudH, a.WudL, a.dub, a.Rb, a.Hst, a.XAh, a.XAl, 2, SM);
    grid.sync();
    ph_proj(a.Hst, a.pw, a.pb, a.GO, a.out, t);
    grid.sync();
  }
}

extern "C" void kernel_launch(void* const* d_in, const int* in_sizes, int n_in,
                              void* d_out, int out_size, void* d_ws, size_t ws_size,
                              hipStream_t stream) {
  (void)in_sizes; (void)n_in; (void)out_size; (void)ws_size;
  Args a;
  a.x    = (const float*)d_in[0];
  a.ycov = (const float*)d_in[1];
  a.emb  = (const float*)d_in[2];
  a.fce  = (const float*)d_in[3];
  a.egw  = (const float*)d_in[4];
  a.egb  = (const float*)d_in[5];
  a.euw  = (const float*)d_in[6];
  a.eub  = (const float*)d_in[7];
  a.dgw  = (const float*)d_in[8];
  a.dgb  = (const float*)d_in[9];
  a.duw  = (const float*)d_in[10];
  a.dub  = (const float*)d_in[11];
  a.pw   = (const float*)d_in[12];
  a.pb   = (const float*)d_in[13];
  a.out  = (float*)d_out;

  char* wsb = (char*)d_ws;
  size_t off = 0;
  auto alloc = [&](size_t bytes) {
    void* p = wsb + off;
    off = (off + bytes + 255) & ~(size_t)255;
    return p;
  };
  a.S1f = (float*)alloc((size_t)Nn * Nn * 4);
  a.S2f = (float*)alloc((size_t)Nn * Nn * 4);
  a.S1h = (u16*)alloc((size_t)Nn * Nn * 2);
  a.S1l = (u16*)alloc((size_t)Nn * Nn * 2);
  a.S2h = (u16*)alloc((size_t)Nn * Nn * 2);
  a.S2l = (u16*)alloc((size_t)Nn * Nn * 2);
  a.Hst = (float*)alloc((size_t)NB * Hc * 4);
  a.XAh = (u16*)alloc((size_t)(NB + 4) * SA * 2);
  a.XAl = (u16*)alloc((size_t)(NB + 4) * SA * 2);
  a.Xth = (u16*)alloc((size_t)Bc * Cc * Nn * 2);
  a.Xtl = (u16*)alloc((size_t)Bc * Cc * Nn * 2);
  a.Rb  = (float*)alloc((size_t)NB * Hc * 4);
  a.DE  = (float*)alloc((size_t)Nn * Bc * Ec * 4);
  a.GO  = (float*)alloc((size_t)NB * 4);
  a.WgeH = (u16*)alloc(128 * KP * 2); a.WgeL = (u16*)alloc(128 * KP * 2);
  a.WueH = (u16*)alloc(64 * KP * 2);  a.WueL = (u16*)alloc(64 * KP * 2);
  a.WgdH = (u16*)alloc(128 * KP * 2); a.WgdL = (u16*)alloc(128 * KP * 2);
  a.WudH = (u16*)alloc(64 * KP * 2);  a.WudL = (u16*)alloc(64 * KP * 2);

  int numCU = 0;
  if (hipDeviceGetAttribute(&numCU, hipDeviceAttributeMultiprocessorCount, 0) !=
          hipSuccess ||
      numCU <= 0)
    numCU = 256;
  int maxb = 0;
  if (hipOccupancyMaxActiveBlocksPerMultiprocessor(&maxb, mega, 256, 0) != hipSuccess ||
      maxb < 1)
    maxb = 1;
  if (maxb > 4) maxb = 4;
  dim3 grid(numCU * maxb);

  void* params[] = {(void*)&a};
  hipLaunchCooperativeKernel((const void*)mega, grid, dim3(256), params, 0, stream);
}

// Round 5
// 6478.889 us; speedup vs baseline: 2.2754x; 2.2754x over previous
//
#include <hip/hip_runtime.h>
#include <math.h>

typedef __attribute__((ext_vector_type(8))) short bf16x8;
typedef __attribute__((ext_vector_type(4))) float f32x4;
typedef unsigned short u16;

namespace {
constexpr int Bc = 64, Tc = 12, Nn = 1024, Hc = 64, Ec = 10;
constexpr int NB = Nn * Bc;  // 65536
constexpr int Cc = 66;       // unified channel count (enc uses 65, col 65 zeroed)
constexpr int SA = 208;      // XA row stride ([X(66)|Y1(66)|Y2(66)|pad10])
constexpr int KP = 224;      // padded K for gate/update GEMMs (7 x 32)
constexpr int KD = Bc * Ec;  // 640, dec gram K
constexpr int TN = Tc * Nn;  // 12288
}

// bank-group swizzle: chunk (r,kc) at 16B-unit ci = r*4 + (kc ^ SWZ(r)) -> 2-way (free)
#define SWZ(r) (((r) >> 1) & 3)

__device__ __forceinline__ void gld16(const void* g, void* l) {
  __builtin_amdgcn_global_load_lds(
      (const __attribute__((address_space(1))) void*)g,
      (__attribute__((address_space(3))) void*)l, 16, 0, 0);
}

// split fp32 -> bf16 hi + bf16 lo (RNE both)
__device__ __forceinline__ void split_bf(float v, u16& h, u16& l) {
  unsigned u = __float_as_uint(v);
  unsigned hu = (u + 0x7FFFu + ((u >> 16) & 1u)) & 0xFFFF0000u;
  h = (u16)(hu >> 16);
  float r = v - __uint_as_float(hu);
  unsigned u2 = __float_as_uint(r);
  l = (u16)((u2 + 0x7FFFu + ((u2 >> 16) & 1u)) >> 16);
}
// single bf16 RNE
__device__ __forceinline__ u16 bf_rne(float v) {
  unsigned u = __float_as_uint(v);
  return (u16)((u + 0x7FFFu + ((u >> 16) & 1u)) >> 16);
}

// ---------- enc gram: G = emb @ emb^T (Kd=10, fp32, cheap) ----------
__global__ __launch_bounds__(256) void k_gram(const float* __restrict__ in, int Kd,
                                              float* __restrict__ G) {
  __shared__ float At[16][64];
  __shared__ float Bt[16][64];
  int i0 = blockIdx.y * 64, j0 = blockIdx.x * 64;
  int tx = threadIdx.x & 15, ty = threadIdx.x >> 4;
  float acc[4][4] = {};
  for (int k0 = 0; k0 < Kd; k0 += 16) {
    for (int u = threadIdx.x; u < 1024; u += 256) {
      int i = u >> 4, k = u & 15;
      At[k][i] = (k0 + k < Kd) ? in[(size_t)(i0 + i) * Kd + k0 + k] : 0.f;
    }
    for (int u = threadIdx.x; u < 1024; u += 256) {
      int j = u >> 4, k = u & 15;
      Bt[k][j] = (k0 + k < Kd) ? in[(size_t)(j0 + j) * Kd + k0 + k] : 0.f;
    }
    __syncthreads();
#pragma unroll
    for (int kk = 0; kk < 16; kk++) {
      float a[4], b[4];
#pragma unroll
      for (int p = 0; p < 4; p++) a[p] = At[kk][ty * 4 + p];
#pragma unroll
      for (int q = 0; q < 4; q++) b[q] = Bt[kk][tx * 4 + q];
#pragma unroll
      for (int p = 0; p < 4; p++)
#pragma unroll
        for (int q = 0; q < 4; q++) acc[p][q] = fmaf(a[p], b[q], acc[p][q]);
    }
    __syncthreads();
  }
  for (int p = 0; p < 4; p++)
    for (int q = 0; q < 4; q++)
      G[(size_t)(i0 + ty * 4 + p) * Nn + j0 + tx * 4 + q] = acc[p][q];
}

// ---------- dec gram via split-MFMA: G = DE @ DE^T, DE hi/lo (Nn x 640) ----------
// BM=64, BN=128, BK=32; 4 waves 2x2, wave tile 32x64
__global__ __launch_bounds__(256) void k_gram_mfma(const u16* __restrict__ Dh,
                                                   const u16* __restrict__ Dl,
                                                   float* __restrict__ G) {
  __shared__ u16 lds[12288];  // Ah(2048) Al(2048) Bh(4096) Bl(4096) = 24KB
  const int tid = threadIdx.x;
  const int wave = tid >> 6, lane = tid & 63;
  const int i0 = blockIdx.y * 64;
  const int j0 = blockIdx.x * 128;
  const int wy = wave >> 1, wx = wave & 1;
  const int m = lane & 15, quad = lane >> 4;

  f32x4 acc[2][4];
  f32x4 z4 = {0.f, 0.f, 0.f, 0.f};
#pragma unroll
  for (int a = 0; a < 2; a++)
#pragma unroll
    for (int q = 0; q < 4; q++) acc[a][q] = z4;

  const int ar = tid >> 2;
  const int akc = (tid & 3) ^ SWZ(ar);

  for (int k0 = 0; k0 < KD; k0 += 32) {
    gld16(Dh + (size_t)(i0 + ar) * KD + k0 + akc * 8, &lds[wave * 512]);
    gld16(Dl + (size_t)(i0 + ar) * KD + k0 + akc * 8, &lds[2048 + wave * 512]);
#pragma unroll
    for (int p = 0; p < 2; p++) {
      int r = p * 64 + (tid >> 2);
      int kc = (tid & 3) ^ SWZ(r);
      gld16(Dh + (size_t)(j0 + r) * KD + k0 + kc * 8, &lds[4096 + p * 2048 + wave * 512]);
      gld16(Dl + (size_t)(j0 + r) * KD + k0 + kc * 8, &lds[8192 + p * 2048 + wave * 512]);
    }
    __syncthreads();

    bf16x8 ah[2], al[2], bh[4], bl[4];
#pragma unroll
    for (int mb = 0; mb < 2; mb++) {
      int r = wy * 32 + mb * 16 + m;
      int ci = r * 4 + (quad ^ SWZ(r));
      ah[mb] = *(const bf16x8*)&lds[ci * 8];
      al[mb] = *(const bf16x8*)&lds[2048 + ci * 8];
    }
#pragma unroll
    for (int nb = 0; nb < 4; nb++) {
      int rj = wx * 64 + nb * 16 + m;
      int cj = rj * 4 + (quad ^ SWZ(rj));
      bh[nb] = *(const bf16x8*)&lds[4096 + cj * 8];
      bl[nb] = *(const bf16x8*)&lds[8192 + cj * 8];
    }
#pragma unroll
    for (int mb = 0; mb < 2; mb++)
#pragma unroll
      for (int nb = 0; nb < 4; nb++) {
        acc[mb][nb] = __builtin_amdgcn_mfma_f32_16x16x32_bf16(ah[mb], bh[nb], acc[mb][nb], 0, 0, 0);
        acc[mb][nb] = __builtin_amdgcn_mfma_f32_16x16x32_bf16(ah[mb], bl[nb], acc[mb][nb], 0, 0, 0);
        acc[mb][nb] = __builtin_amdgcn_mfma_f32_16x16x32_bf16(al[mb], bh[nb], acc[mb][nb], 0, 0, 0);
      }
    __syncthreads();
  }

#pragma unroll
  for (int mb = 0; mb < 2; mb++)
#pragma unroll
    for (int nb = 0; nb < 4; nb++) {
      int col = j0 + wx * 64 + nb * 16 + m;
#pragma unroll
      for (int p = 0; p < 4; p++) {
        int row = i0 + wy * 32 + mb * 16 + quad * 4 + p;
        G[(size_t)row * Nn + col] = acc[mb][nb][p];
      }
    }
}

// ---------- S = row_softmax(relu(G)) ----------
__global__ __launch_bounds__(256) void k_softmax(const float* __restrict__ G,
                                                 float* __restrict__ S) {
  __shared__ float sred[8];
  int n = blockIdx.x;
  float v[4];
#pragma unroll
  for (int i = 0; i < 4; i++)
    v[i] = fmaxf(G[(size_t)n * Nn + threadIdx.x + i * 256], 0.f);
  float mx = fmaxf(fmaxf(v[0], v[1]), fmaxf(v[2], v[3]));
  for (int off = 32; off > 0; off >>= 1) mx = fmaxf(mx, __shfl_down(mx, off));
  if ((threadIdx.x & 63) == 0) sred[threadIdx.x >> 6] = mx;
  __syncthreads();
  float rmax = fmaxf(fmaxf(sred[0], sred[1]), fmaxf(sred[2], sred[3]));
  float s = 0.f;
#pragma unroll
  for (int i = 0; i < 4; i++) { v[i] = expf(v[i] - rmax); s += v[i]; }
  for (int off = 32; off > 0; off >>= 1) s += __shfl_down(s, off);
  if ((threadIdx.x & 63) == 0) sred[4 + (threadIdx.x >> 6)] = s;
  __syncthreads();
  float inv = 1.f / (sred[4] + sred[5] + sred[6] + sred[7]);
#pragma unroll
  for (int i = 0; i < 4; i++) S[(size_t)n * Nn + threadIdx.x + i * 256] = v[i] * inv;
}

// ---------- S2 = 2*S@S - I (fp32) ----------
__global__ __launch_bounds__(256) void k_s2(const float* __restrict__ S,
                                            float* __restrict__ S2) {
  __shared__ float At[16][64];
  __shared__ float Bt[16][64];
  int i0 = blockIdx.y * 64, j0 = blockIdx.x * 64;
  int tx = threadIdx.x & 15, ty = threadIdx.x >> 4;
  float acc[4][4] = {};
  for (int k0 = 0; k0 < Nn; k0 += 16) {
    for (int u = threadIdx.x; u < 1024; u += 256) {
      int i = u >> 4, k = u & 15;
      At[k][i] = S[(size_t)(i0 + i) * Nn + k0 + k];
    }
    for (int u = threadIdx.x; u < 1024; u += 256) {
      int k = u >> 6, j = u & 63;
      Bt[k][j] = S[(size_t)(k0 + k) * Nn + j0 + j];
    }
    __syncthreads();
#pragma unroll
    for (int kk = 0; kk < 16; kk++) {
      float a[4], b[4];
#pragma unroll
      for (int p = 0; p < 4; p++) a[p] = At[kk][ty * 4 + p];
#pragma unroll
      for (int q = 0; q < 4; q++) b[q] = Bt[kk][tx * 4 + q];
#pragma unroll
      for (int p = 0; p < 4; p++)
#pragma unroll
        for (int q = 0; q < 4; q++) acc[p][q] = fmaf(a[p], b[q], acc[p][q]);
    }
    __syncthreads();
  }
  for (int p = 0; p < 4; p++)
    for (int q = 0; q < 4; q++) {
      int i = i0 + ty * 4 + p, j = j0 + tx * 4 + q;
      S2[(size_t)i * Nn + j] = 2.f * acc[p][q] - (i == j ? 1.f : 0.f);
    }
}

// ---------- split S1,S2 fp32 -> bf16 hi/lo ----------
__global__ __launch_bounds__(256) void k_split2(const float* __restrict__ A,
                                                const float* __restrict__ B,
                                                u16* __restrict__ Ah, u16* __restrict__ Al,
                                                u16* __restrict__ Bh, u16* __restrict__ Bl) {
  int i = blockIdx.x * 256 + threadIdx.x;
  if (i >= Nn * Nn) return;
  u16 h, l;
  split_bf(A[i], h, l); Ah[i] = h; Al[i] = l;
  split_bf(B[i], h, l); Bh[i] = h; Bl[i] = l;
}

// ---------- Wt prep ----------
__global__ __launch_bounds__(256) void k_prep_wt(const float* __restrict__ W, int Csrc,
                                                 int ncol, u16* __restrict__ Wh,
                                                 u16* __restrict__ Wl) {
  int idx = blockIdx.x * 256 + threadIdx.x;
  if (idx >= ncol * KP) return;
  int n = idx / KP, kp = idx % KP;
  int chunk = kp / Cc, c = kp % Cc;
  float v = 0.f;
  if (kp < 3 * Cc && c < Csrc) v = W[((size_t)chunk * Csrc + c) * ncol + n];
  u16 h, l;
  split_bf(v, h, l);
  Wh[idx] = h; Wl[idx] = l;
}

// ---------- fill enc: XA col0 = x_t (hi/lo) + Xth row (b*66+0) ----------
__global__ __launch_bounds__(256) void k_fill_enc(const float* __restrict__ x,
                                                  u16* __restrict__ XAh, u16* __restrict__ XAl,
                                                  u16* __restrict__ Xth, int t) {
  int idx = blockIdx.x * 256 + threadIdx.x;
  if (idx >= NB) return;
  int n = idx >> 6, b = idx & 63;
  float v = x[(size_t)b * TN + t * Nn + n];
  u16 h, l;
  split_bf(v, h, l);
  XAh[(size_t)idx * SA] = h; XAl[(size_t)idx * SA] = l;
  Xth[(size_t)b * Cc * Nn + n] = bf_rne(v);
}

// ---------- dec init: col0 = x[:,T-1], col1 = ycov[0] ----------
__global__ __launch_bounds__(256) void k_dec_init(const float* __restrict__ x,
                                                  const float* __restrict__ ycov,
                                                  u16* __restrict__ XAh, u16* __restrict__ XAl,
                                                  u16* __restrict__ Xth) {
  int idx = blockIdx.x * 256 + threadIdx.x;
  if (idx >= NB) return;
  int n = idx >> 6, b = idx & 63;
  float v0 = x[(size_t)b * TN + (size_t)(Tc - 1) * Nn + n];
  float v1 = ycov[(size_t)b * TN + n];
  u16 h, l;
  split_bf(v0, h, l);
  XAh[(size_t)idx * SA] = h; XAl[(size_t)idx * SA] = l;
  split_bf(v1, h, l);
  XAh[(size_t)idx * SA + 1] = h; XAl[(size_t)idx * SA + 1] = l;
  Xth[((size_t)b * Cc) * Nn + n] = bf_rne(v0);
  Xth[((size_t)b * Cc + 1) * Nn + n] = bf_rne(v1);
}

// ---------- Y1 = S@X, Y2 = S2@X; S split hi/lo, X single bf16 (2-term) ----------
// BM=64 (n), BN=128 (j=(b,c)), BK=32; 4 waves 2x2, wave tile 32x64
__global__ __launch_bounds__(256) void k_ygemm(const u16* __restrict__ S1h, const u16* __restrict__ S1l,
                                               const u16* __restrict__ S2h, const u16* __restrict__ S2l,
                                               const u16* __restrict__ Xth,
                                               u16* __restrict__ XAh, u16* __restrict__ XAl) {
  __shared__ u16 lds[12288];  // A: 4x2048 (S1h,S1l,S2h,S2l), B: 2x2048 (Xth) = 24KB
  const int tid = threadIdx.x;
  const int wave = tid >> 6, lane = tid & 63;
  const int i0 = blockIdx.y * 64;
  const int j0 = blockIdx.x * 128;
  const int wy = wave >> 1, wx = wave & 1;
  const int m = lane & 15, quad = lane >> 4;

  f32x4 acc1[2][4], acc2[2][4];
  f32x4 z4 = {0.f, 0.f, 0.f, 0.f};
#pragma unroll
  for (int a = 0; a < 2; a++)
#pragma unroll
    for (int q = 0; q < 4; q++) { acc1[a][q] = z4; acc2[a][q] = z4; }

  const int ar = tid >> 2;
  const int akc = (tid & 3) ^ SWZ(ar);
  const u16* amat[4] = {S1h, S1l, S2h, S2l};

  for (int k0 = 0; k0 < Nn; k0 += 32) {
#pragma unroll
    for (int s = 0; s < 4; s++)
      gld16(amat[s] + (size_t)(i0 + ar) * Nn + k0 + akc * 8, &lds[s * 2048 + wave * 512]);
#pragma unroll
    for (int p = 0; p < 2; p++) {
      int r = p * 64 + (tid >> 2);
      int kc = (tid & 3) ^ SWZ(r);
      gld16(Xth + (size_t)(j0 + r) * Nn + k0 + kc * 8, &lds[8192 + p * 2048 + wave * 512]);
    }
    __syncthreads();

    bf16x8 a1h[2], a1l[2], a2h[2], a2l[2], bh[4];
#pragma unroll
    for (int mb = 0; mb < 2; mb++) {
      int r = wy * 32 + mb * 16 + m;
      int ci = r * 4 + (quad ^ SWZ(r));
      a1h[mb] = *(const bf16x8*)&lds[0 * 2048 + ci * 8];
      a1l[mb] = *(const bf16x8*)&lds[1 * 2048 + ci * 8];
      a2h[mb] = *(const bf16x8*)&lds[2 * 2048 + ci * 8];
      a2l[mb] = *(const bf16x8*)&lds[3 * 2048 + ci * 8];
    }
#pragma unroll
    for (int nb = 0; nb < 4; nb++) {
      int rj = wx * 64 + nb * 16 + m;
      int cj = rj * 4 + (quad ^ SWZ(rj));
      bh[nb] = *(const bf16x8*)&lds[8192 + cj * 8];
    }
#pragma unroll
    for (int mb = 0; mb < 2; mb++)
#pragma unroll
      for (int nb = 0; nb < 4; nb++) {
        acc1[mb][nb] = __builtin_amdgcn_mfma_f32_16x16x32_bf16(a1h[mb], bh[nb], acc1[mb][nb], 0, 0, 0);
        acc1[mb][nb] = __builtin_amdgcn_mfma_f32_16x16x32_bf16(a1l[mb], bh[nb], acc1[mb][nb], 0, 0, 0);
        acc2[mb][nb] = __builtin_amdgcn_mfma_f32_16x16x32_bf16(a2h[mb], bh[nb], acc2[mb][nb], 0, 0, 0);
        acc2[mb][nb] = __builtin_amdgcn_mfma_f32_16x16x32_bf16(a2l[mb], bh[nb], acc2[mb][nb], 0, 0, 0);
      }
    __syncthreads();
  }

#pragma unroll
  for (int mb = 0; mb < 2; mb++)
#pragma unroll
    for (int nb = 0; nb < 4; nb++) {
      int col = j0 + wx * 64 + nb * 16 + m;
      int bb = col / Cc, cc = col % Cc;
#pragma unroll
      for (int p = 0; p < 4; p++) {
        int row = i0 + wy * 32 + mb * 16 + quad * 4 + p;
        size_t base = ((size_t)row * 64 + bb) * SA;
        u16 vh, vl;
        split_bf(acc1[mb][nb][p], vh, vl);
        XAh[base + 66 + cc] = vh; XAl[base + 66 + cc] = vl;
        split_bf(acc2[mb][nb][p], vh, vl);
        XAh[base + 132 + cc] = vh; XAl[base + 132 + cc] = vl;
      }
    }
}

// ---------- gate: sigmoid(XA@W^T+b) -> Rb; z*h -> XA state cols + Xth ----------
// BM=128, BN=128, BK=32, K=224
__global__ __launch_bounds__(256) void k_gate(const u16* __restrict__ XAh, const u16* __restrict__ XAl,
                                              const u16* __restrict__ Wh, const u16* __restrict__ Wl,
                                              const float* __restrict__ bias,
                                              const float* __restrict__ hst,
                                              float* __restrict__ Rb,
                                              u16* __restrict__ XAho, u16* __restrict__ XAlo,
                                              u16* __restrict__ Xth, int off) {
  __shared__ u16 lds[4 * 4096];  // 32KB
  const int tid = threadIdx.x;
  const int wave = tid >> 6, lane = tid & 63;
  const int r0 = blockIdx.x * 128;
  const int wy = wave >> 1, wx = wave & 1;
  const int m = lane & 15, quad = lane >> 4;

  f32x4 acc[4][4];
  f32x4 z4 = {0.f, 0.f, 0.f, 0.f};
#pragma unroll
  for (int a = 0; a < 4; a++)
#pragma unroll
    for (int q = 0; q < 4; q++) acc[a][q] = z4;

  for (int kt = 0; kt < 7; kt++) {
    int k0 = kt * 32;
#pragma unroll
    for (int p = 0; p < 2; p++) {
      int r = p * 64 + (tid >> 2);
      int kc = (tid & 3) ^ SWZ(r);
      gld16(XAh + (size_t)(r0 + r) * SA + k0 + kc * 8, &lds[p * 2048 + wave * 512]);
      gld16(XAl + (size_t)(r0 + r) * SA + k0 + kc * 8, &lds[4096 + p * 2048 + wave * 512]);
      gld16(Wh + (size_t)r * KP + k0 + kc * 8, &lds[8192 + p * 2048 + wave * 512]);
      gld16(Wl + (size_t)r * KP + k0 + kc * 8, &lds[12288 + p * 2048 + wave * 512]);
    }
    __syncthreads();

    bf16x8 ah[4], al[4], bh[4], bl[4];
#pragma unroll
    for (int mb = 0; mb < 4; mb++) {
      int r = wy * 64 + mb * 16 + m;
      int ci = r * 4 + (quad ^ SWZ(r));
      ah[mb] = *(const bf16x8*)&lds[ci * 8];
      al[mb] = *(const bf16x8*)&lds[4096 + ci * 8];
    }
#pragma unroll
    for (int nb = 0; nb < 4; nb++) {
      int rj = wx * 64 + nb * 16 + m;
      int cj = rj * 4 + (quad ^ SWZ(rj));
      bh[nb] = *(const bf16x8*)&lds[8192 + cj * 8];
      bl[nb] = *(const bf16x8*)&lds[12288 + cj * 8];
    }
#pragma unroll
    for (int mb = 0; mb < 4; mb++)
#pragma unroll
      for (int nb = 0; nb < 4; nb++) {
        acc[mb][nb] = __builtin_amdgcn_mfma_f32_16x16x32_bf16(ah[mb], bh[nb], acc[mb][nb], 0, 0, 0);
        acc[mb][nb] = __builtin_amdgcn_mfma_f32_16x16x32_bf16(ah[mb], bl[nb], acc[mb][nb], 0, 0, 0);
        acc[mb][nb] = __builtin_amdgcn_mfma_f32_16x16x32_bf16(al[mb], bh[nb], acc[mb][nb], 0, 0, 0);
      }
    __syncthreads();
  }

#pragma unroll
  for (int mb = 0; mb < 4; mb++)
#pragma unroll
    for (int nb = 0; nb < 4; nb++) {
      int col = wx * 64 + nb * 16 + m;
      float bv = bias[col];
#pragma unroll
      for (int p = 0; p < 4; p++) {
        int row = r0 + wy * 64 + mb * 16 + quad * 4 + p;
        float sg = 1.f / (1.f + expf(-(acc[mb][nb][p] + bv)));
        if (col < 64) {
          float v = sg * hst[(size_t)row * 64 + col];
          u16 vh, vl;
          split_bf(v, vh, vl);
          size_t a = (size_t)row * SA + off + col;
          XAho[a] = vh; XAlo[a] = vl;
          int n = row >> 6, b = row & 63;
          Xth[((size_t)b * Cc + off + col) * Nn + n] = bf_rne(v);
        } else {
          Rb[(size_t)row * 64 + col - 64] = sg;
        }
      }
    }
}

// ---------- update: hc=tanh(XA@Wu^T+b); h=r*h+(1-r)*hc -> Hst, XA state, Xth ----------
// BM=128, BN=64, BK=32
__global__ __launch_bounds__(256) void k_upd(const u16* __restrict__ XAh, const u16* __restrict__ XAl,
                                             const u16* __restrict__ Wh, const u16* __restrict__ Wl,
                                             const float* __restrict__ bias,
                                             const float* __restrict__ Rb,
                                             float* __restrict__ h,
                                             u16* __restrict__ XAho, u16* __restrict__ XAlo,
                                             u16* __restrict__ Xth, int off_next) {
  __shared__ u16 lds[2 * 4096 + 2 * 2048];  // 24KB
  const int tid = threadIdx.x;
  const int wave = tid >> 6, lane = tid & 63;
  const int r0 = blockIdx.x * 128;
  const int wy = wave >> 1, wx = wave & 1;
  const int m = lane & 15, quad = lane >> 4;

  f32x4 acc[4][2];
  f32x4 z4 = {0.f, 0.f, 0.f, 0.f};
#pragma unroll
  for (int a = 0; a < 4; a++) { acc[a][0] = z4; acc[a][1] = z4; }

  for (int kt = 0; kt < 7; kt++) {
    int k0 = kt * 32;
#pragma unroll
    for (int p = 0; p < 2; p++) {
      int r = p * 64 + (tid >> 2);
      int kc = (tid & 3) ^ SWZ(r);
      gld16(XAh + (size_t)(r0 + r) * SA + k0 + kc * 8, &lds[p * 2048 + wave * 512]);
      gld16(XAl + (size_t)(r0 + r) * SA + k0 + kc * 8, &lds[4096 + p * 2048 + wave * 512]);
    }
    {
      int r = tid >> 2;
      int kc = (tid & 3) ^ SWZ(r);
      gld16(Wh + (size_t)r * KP + k0 + kc * 8, &lds[8192 + wave * 512]);
      gld16(Wl + (size_t)r * KP + k0 + kc * 8, &lds[10240 + wave * 512]);
    }
    __syncthreads();

    bf16x8 ah[4], al[4], bh[2], bl[2];
#pragma unroll
    for (int mb = 0; mb < 4; mb++) {
      int r = wy * 64 + mb * 16 + m;
      int ci = r * 4 + (quad ^ SWZ(r));
      ah[mb] = *(const bf16x8*)&lds[ci * 8];
      al[mb] = *(const bf16x8*)&lds[4096 + ci * 8];
    }
#pragma unroll
    for (int nb = 0; nb < 2; nb++) {
      int rj = wx * 32 + nb * 16 + m;
      int cj = rj * 4 + (quad ^ SWZ(rj));
      bh[nb] = *(const bf16x8*)&lds[8192 + cj * 8];
      bl[nb] = *(const bf16x8*)&lds[10240 + cj * 8];
    }
#pragma unroll
    for (int mb = 0; mb < 4; mb++)
#pragma unroll
      for (int nb = 0; nb < 2; nb++) {
        acc[mb][nb] = __builtin_amdgcn_mfma_f32_16x16x32_bf16(ah[mb], bh[nb], acc[mb][nb], 0, 0, 0);
        acc[mb][nb] = __builtin_amdgcn_mfma_f32_16x16x32_bf16(ah[mb], bl[nb], acc[mb][nb], 0, 0, 0);
        acc[mb][nb] = __builtin_amdgcn_mfma_f32_16x16x32_bf16(al[mb], bh[nb], acc[mb][nb], 0, 0, 0);
      }
    __syncthreads();
  }

#pragma unroll
  for (int mb = 0; mb < 4; mb++)
#pragma unroll
    for (int nb = 0; nb < 2; nb++) {
      int col = wx * 32 + nb * 16 + m;
      float bv = bias[col];
#pragma unroll
      for (int p = 0; p < 4; p++) {
        int row = r0 + wy * 64 + mb * 16 + quad * 4 + p;
        float hc = tanhf(acc[mb][nb][p] + bv);
        size_t idx = (size_t)row * 64 + col;
        float rr = Rb[idx];
        float hn = rr * h[idx] + (1.f - rr) * hc;
        h[idx] = hn;
        u16 vh, vl;
        split_bf(hn, vh, vl);
        size_t a = (size_t)row * SA + off_next + col;
        XAho[a] = vh; XAlo[a] = vl;
        int n = row >> 6, b = row & 63;
        Xth[((size_t)b * Cc + off_next + col) * Nn + n] = bf_rne(hn);
      }
    }
}

// ---------- de = h @ FC_E, write hi/lo directly ----------
__global__ __launch_bounds__(256) void k_de(const float* __restrict__ h,
                                            const float* __restrict__ fc,
                                            u16* __restrict__ Dh, u16* __restrict__ Dl) {
  __shared__ float fcs[Hc * Ec];
  for (int j = threadIdx.x; j < Hc * Ec; j += 256) fcs[j] = fc[j];
  __syncthreads();
  int idx = blockIdx.x * 256 + threadIdx.x;
  if (idx >= Nn * KD) return;
  int n = idx / KD;
  int rem = idx % KD;
  int b = rem / Ec, e = rem % Ec;
  const float* hp = h + (size_t)n * (Bc * Hc) + (size_t)b * Hc;
  float acc = 0.f;
#pragma unroll 8
  for (int hh = 0; hh < Hc; hh++) acc = fmaf(hp[hh], fcs[hh * Ec + e], acc);
  u16 vh, vl;
  split_bf(acc, vh, vl);
  Dh[idx] = vh; Dl[idx] = vl;
}

// ---------- proj + fill next dec step: go = h@pw+pb; out; XA col0/1 + Xth ----------
__global__ __launch_bounds__(256) void k_proj_fill(const float* __restrict__ h,
                                                   const float* __restrict__ pw,
                                                   const float* __restrict__ pb,
                                                   const float* __restrict__ ycov,
                                                   u16* __restrict__ XAh, u16* __restrict__ XAl,
                                                   u16* __restrict__ Xth,
                                                   float* __restrict__ out, int t) {
  int idx = blockIdx.x * 256 + threadIdx.x;
  if (idx >= NB) return;
  int n = idx >> 6, b = idx & 63;
  const float* hp = h + (size_t)idx * Hc;
  float acc = pb[0];
#pragma unroll 8
  for (int i = 0; i < Hc; i++) acc = fmaf(hp[i], pw[i], acc);
  out[(size_t)b * TN + (size_t)t * Nn + n] = acc;
  if (t + 1 < Tc) {
    float v1 = ycov[(size_t)b * TN + (size_t)(t + 1) * Nn + n];
    u16 hh, ll;
    split_bf(acc, hh, ll);
    XAh[(size_t)idx * SA] = hh; XAl[(size_t)idx * SA] = ll;
    split_bf(v1, hh, ll);
    XAh[(size_t)idx * SA + 1] = hh; XAl[(size_t)idx * SA + 1] = ll;
    Xth[((size_t)b * Cc) * Nn + n] = bf_rne(acc);
    Xth[((size_t)b * Cc + 1) * Nn + n] = bf_rne(v1);
  }
}

extern "C" void kernel_launch(void* const* d_in, const int* in_sizes, int n_in,
                              void* d_out, int out_size, void* d_ws, size_t ws_size,
                              hipStream_t stream) {
  (void)in_sizes; (void)n_in; (void)out_size; (void)ws_size;
  const float* x    = (const float*)d_in[0];
  const float* ycov = (const float*)d_in[1];
  const float* emb  = (const float*)d_in[2];
  const float* fce  = (const float*)d_in[3];
  const float* egw  = (const float*)d_in[4];
  const float* egb  = (const float*)d_in[5];
  const float* euw  = (const float*)d_in[6];
  const float* eub  = (const float*)d_in[7];
  const float* dgw  = (const float*)d_in[8];
  const float* dgb  = (const float*)d_in[9];
  const float* duw  = (const float*)d_in[10];
  const float* dub  = (const float*)d_in[11];
  const float* pw   = (const float*)d_in[12];
  const float* pb   = (const float*)d_in[13];
  float* out = (float*)d_out;

  char* wsb = (char*)d_ws;
  size_t off = 0;
  auto alloc = [&](size_t bytes) {
    void* p = wsb + off;
    off = (off + bytes + 255) & ~(size_t)255;
    return p;
  };
  float* S1f = (float*)alloc((size_t)Nn * Nn * 4);
  float* S2f = (float*)alloc((size_t)Nn * Nn * 4);
  u16* S1h = (u16*)alloc((size_t)Nn * Nn * 2);
  u16* S1l = (u16*)alloc((size_t)Nn * Nn * 2);
  u16* S2h = (u16*)alloc((size_t)Nn * Nn * 2);
  u16* S2l = (u16*)alloc((size_t)Nn * Nn * 2);
  float* Hst = (float*)alloc((size_t)NB * Hc * 4);
  u16* XAh = (u16*)alloc((size_t)(NB + 4) * SA * 2);
  u16* XAl = (u16*)alloc((size_t)(NB + 4) * SA * 2);
  u16* Xth = (u16*)alloc((size_t)Bc * Cc * Nn * 2);
  float* Rb = (float*)alloc((size_t)NB * Hc * 4);
  u16* DEh = (u16*)alloc((size_t)Nn * KD * 2);
  u16* DEl = (u16*)alloc((size_t)Nn * KD * 2);
  u16* WgeH = (u16*)alloc(128 * KP * 2); u16* WgeL = (u16*)alloc(128 * KP * 2);
  u16* WueH = (u16*)alloc(64 * KP * 2);  u16* WueL = (u16*)alloc(64 * KP * 2);
  u16* WgdH = (u16*)alloc(128 * KP * 2); u16* WgdL = (u16*)alloc(128 * KP * 2);
  u16* WudH = (u16*)alloc(64 * KP * 2);  u16* WudL = (u16*)alloc(64 * KP * 2);

  hipMemsetAsync(Hst, 0, (size_t)NB * Hc * 4, stream);
  hipMemsetAsync(XAh, 0, (size_t)(NB + 4) * SA * 2, stream);
  hipMemsetAsync(XAl, 0, (size_t)(NB + 4) * SA * 2, stream);
  hipMemsetAsync(Xth, 0, (size_t)Bc * Cc * Nn * 2, stream);

  k_prep_wt<<<(128 * KP + 255) / 256, 256, 0, stream>>>(egw, 65, 128, WgeH, WgeL);
  k_prep_wt<<<(64 * KP + 255) / 256, 256, 0, stream>>>(euw, 65, 64, WueH, WueL);
  k_prep_wt<<<(128 * KP + 255) / 256, 256, 0, stream>>>(dgw, 66, 128, WgdH, WgdL);
  k_prep_wt<<<(64 * KP + 255) / 256, 256, 0, stream>>>(duw, 66, 64, WudH, WudL);

  // encoder supports
  k_gram<<<dim3(16, 16), 256, 0, stream>>>(emb, Ec, S2f);
  k_softmax<<<Nn, 256, 0, stream>>>(S2f, S1f);
  k_s2<<<dim3(16, 16), 256, 0, stream>>>(S1f, S2f);
  k_split2<<<(Nn * Nn + 255) / 256, 256, 0, stream>>>(S1f, S2f, S1h, S1l, S2h, S2l);

  const int gNB = NB / 256;

  for (int t = 0; t < Tc; t++) {
    k_fill_enc<<<gNB, 256, 0, stream>>>(x, XAh, XAl, Xth, t);
    k_ygemm<<<dim3(33, 16), 256, 0, stream>>>(S1h, S1l, S2h, S2l, Xth, XAh, XAl);
    k_gate<<<512, 256, 0, stream>>>(XAh, XAl, WgeH, WgeL, egb, Hst, Rb, XAh, XAl, Xth, 1);
    k_ygemm<<<dim3(33, 16), 256, 0, stream>>>(S1h, S1l, S2h, S2l, Xth, XAh, XAl);
    k_upd<<<512, 256, 0, stream>>>(XAh, XAl, WueH, WueL, eub, Rb, Hst, XAh, XAl, Xth,
                                   (t == Tc - 1) ? 2 : 1);
  }

  // decoder supports
  k_de<<<(Nn * KD + 255) / 256, 256, 0, stream>>>(Hst, fce, DEh, DEl);
  k_gram_mfma<<<dim3(8, 16), 256, 0, stream>>>(DEh, DEl, S2f);
  k_softmax<<<Nn, 256, 0, stream>>>(S2f, S1f);
  k_s2<<<dim3(16, 16), 256, 0, stream>>>(S1f, S2f);
  k_split2<<<(Nn * Nn + 255) / 256, 256, 0, stream>>>(S1f, S2f, S1h, S1l, S2h, S2l);
  k_dec_init<<<gNB, 256, 0, stream>>>(x, ycov, XAh, XAl, Xth);

  for (int t = 0; t < Tc; t++) {
    k_ygemm<<<dim3(33, 16), 256, 0, stream>>>(S1h, S1l, S2h, S2l, Xth, XAh, XAl);
    k_gate<<<512, 256, 0, stream>>>(XAh, XAl, WgdH, WgdL, dgb, Hst, Rb, XAh, XAl, Xth, 2);
    k_ygemm<<<dim3(33, 16), 256, 0, stream>>>(S1h, S1l, S2h, S2l, Xth, XAh, XAl);
    k_upd<<<512, 256, 0, stream>>>(XAh, XAl, WudH, WudL, dub, Rb, Hst, XAh, XAl, Xth, 2);
    k_proj_fill<<<gNB, 256, 0, stream>>>(Hst, pw, pb, ycov, XAh, XAl, Xth, out, t);
  }
}